// Round 7
// baseline (214.852 us; speedup 1.0000x reference)
//
#include <hip/hip_runtime.h>

typedef __bf16 bf16;
typedef __attribute__((ext_vector_type(8))) __bf16 bf16x8;
typedef __attribute__((ext_vector_type(4))) __bf16 bf16x4;
typedef __attribute__((ext_vector_type(4))) float f32x4;

__device__ __forceinline__ void gload16(const void* g, void* l) {
  __builtin_amdgcn_global_load_lds(
      (__attribute__((address_space(1))) void*)(g),
      (__attribute__((address_space(3))) void*)(l), 16, 0, 0);
}

// ---------------------------------------------------------------------------
// Workspace layout (bytes):
//   xh  : NHWC padded input, bf16 [130][130][512]        = 17,305,600
//   w1t : conv1 weights,     bf16 [9][512 oc][512 c]     =  4,718,592
//   w2p : packed head wts,   bf16 [80 oc2][512 c]        =     81,920
//   mid : conv1 output NHWC, bf16 [16384 px][512 oc]     = 16,777,216
// ---------------------------------------------------------------------------
#define WS_XH   0
#define WS_W1T  17305600
#define WS_W2P  22024192
#define WS_MID  22106112

#define OUT_CLS 786432
#define OUT_ROI 1179648

// ---------------- fused prep: border | w1 repack | w2 pack | transpose -----
__global__ void prep_all(int4* __restrict__ xh4,
                         const float* __restrict__ w1, bf16* __restrict__ w1t,
                         const float* __restrict__ loc_w,
                         const float* __restrict__ score_w,
                         bf16* __restrict__ w2p,
                         const float* __restrict__ x, bf16* __restrict__ xh) {
  __shared__ float lds[64][65];
  float* ldsf = &lds[0][0];
  const int t = threadIdx.x;
  const int b = blockIdx.x;
  if (b < 132) {                       // ---- xh halo border zeroing
    const int4 z = make_int4(0, 0, 0, 0);
    if (b < 130) {
      if (t < 64)       xh4[(b * 130 + 0) * 64 + t] = z;
      else if (t < 128) xh4[(b * 130 + 129) * 64 + (t - 64)] = z;
    } else {
      const int r = (b == 130) ? 0 : 129;
      for (int i = t; i < 8320; i += 256) xh4[r * 8320 + i] = z;
    }
  } else if (b < 1156) {               // ---- w1 [oc][c][3][3] -> w1t[j][oc][c]
    const int bb = b - 132;
    const long base = (long)bb * 2304;
#pragma unroll
    for (int i = 0; i < 9; ++i) ldsf[i * 256 + t] = w1[base + i * 256 + t];
    __syncthreads();
    const int pair0 = bb * 256;        // pair = oc*512 + c
#pragma unroll
    for (int j = 0; j < 9; ++j)
      w1t[(long)j * 262144 + pair0 + t] = (bf16)ldsf[t * 9 + j];
  } else if (b < 1316) {               // ---- pack loc_w+score_w -> w2p[80][512]
    const int idx = (b - 1156) * 256 + t;
    const int c  = idx & 511;
    const int oc = idx >> 9;
    float v = 0.f;
    if (oc < 48)      v = loc_w[oc * 512 + c];
    else if (oc < 72) v = score_w[(oc - 48) * 512 + c];
    w2p[idx] = (bf16)v;
  } else {                             // ---- NCHW fp32 -> NHWC bf16 transpose
    const int bb   = b - 1316;
    const int ct   = bb & 7;
    const int colt = (bb >> 3) & 1;
    const int r    = 1 + (bb >> 4);
    const int c0   = ct * 64;
    const int col0 = 1 + colt * 64;
    const int lcol = t & 63;
    const int coff = t >> 6;
#pragma unroll
    for (int i = 0; i < 16; ++i) {
      const int cl = coff + i * 4;
      lds[cl][lcol] = x[(long)(c0 + cl) * 16384 + (r - 1) * 128 + (col0 - 1) + lcol];
    }
    __syncthreads();
#pragma unroll
    for (int i = 0; i < 2; ++i) {
      const int idx = i * 256 + t;
      const int pxl = idx >> 3;
      const int oct = idx & 7;
      bf16x8 v;
#pragma unroll
      for (int e = 0; e < 8; ++e) v[e] = (bf16)lds[oct * 8 + e][pxl];
      *(bf16x8*)(xh + (long)(r * 130 + col0 + pxl) * 512 + c0 + oct * 8) = v;
    }
  }
}

// ---------------- conv1: fat-wave implicit GEMM, 3-deep pipeline ------------
// Round-6 analysis: slot time == LDS-pipe traffic (96 KB per slot-index at
// ~60-85 B/cyc). LDS bytes/MFMA for a wave tile m x n (16-units) is
// (m+n)/(m*n) KB -> 64x64 = 512 B. This kernel: 64x128 wave tiles
// (acc[4][8]) -> 375 B/MFMA, and B-staging amortized over 256 px.
// Per-CU LDS traffic drops 13.8 -> 10.4 MB (-25%).
// Block = 128oc x 256px (one h-pair), 4 waves (wr=oc-half, wc=px-half).
// Grid 256 = 4 oc-tiles x 64 h-pairs, 1 block/CU, 1 wave/SIMD; latency
// covered by the 3-deep rotation (loads issued ~2 slots = ~2500 cyc ahead;
// 6 gloads/wave/stage -> s_waitcnt vmcnt(6) waits only the oldest stage).
__global__ __launch_bounds__(256, 1) void conv1_gemm(
    const bf16* __restrict__ w1t, const bf16* __restrict__ xh,
    const float* __restrict__ b1, bf16* __restrict__ mid) {
  __shared__ bf16 A0[4096], A1[4096], A2[4096];      //  8 KB each: 128oc x 32c
  __shared__ bf16 B0[8192], B1[8192], B2[8192];      // 16 KB each: 256px x 32c
  const int tid  = threadIdx.x;
  const int wave = tid >> 6;
  const int lane = tid & 63;
  const int quad = lane >> 4;
  const int l15  = lane & 15;
  const int wr = wave >> 1, wc = wave & 1;   // oc-half / px-half
  const int blk  = blockIdx.x;
  const int oc_t = (blk >> 3) & 3;                      // oc tile (128)
  const int hp   = ((blk & 7) << 3) | (blk >> 5);       // h-pair, XCD-banded
  const int h0   = hp * 2;
  const char* w1tB = (const char*)w1t + (long)oc_t * 131072;
  const char* xhB  = (const char*)xh;
  const int srow = lane >> 2;                               // 16 rows/call
  const int ssw  = (((lane & 3) ^ ((lane >> 3) & 3)) << 4); // swizzled chunk
  const int swq  = (quad ^ ((l15 >> 1) & 3)) << 3;          // swizzled frag

  auto stage = [&](int s, bf16* At, bf16* Bt) {   // 6 gloads per wave
    const int j  = s >> 4, ck = s & 15;
    const int ky = j / 3, kx = j - ky * 3;
    const char* aB = w1tB + (long)j * 524288 + ck * 64;
#pragma unroll
    for (int c = 0; c < 2; ++c) {                 // A: 128 rows, 2 calls/wave
      const int r0 = wave * 32 + c * 16;
      gload16(aB + (long)(r0 + srow) * 1024 + ssw, (char*)At + r0 * 64);
    }
#pragma unroll
    for (int c = 0; c < 4; ++c) {                 // B: 256 px, 4 calls/wave
      const int r0 = wave * 64 + c * 16;          // p = r0 + srow
      const int hh = h0 + (r0 >> 7) + ky;         // uniform within call
      const int w0 = (r0 & 127) + kx;
      gload16(xhB + (long)(hh * 130 + w0 + srow) * 1024 + ck * 64 + ssw,
              (char*)Bt + r0 * 64);
    }
  };

  f32x4 acc[4][8];
#pragma unroll
  for (int i = 0; i < 4; ++i)
#pragma unroll
    for (int k = 0; k < 8; ++k) acc[i][k] = (f32x4){0.f, 0.f, 0.f, 0.f};

  auto compute = [&](const bf16* A, const bf16* B) {
    bf16x8 af[4], bfr[8];
#pragma unroll
    for (int mi = 0; mi < 4; ++mi)
      af[mi] = *(const bf16x8*)&A[(wr * 64 + mi * 16 + l15) * 32 + swq];
#pragma unroll
    for (int ni = 0; ni < 8; ++ni)
      bfr[ni] = *(const bf16x8*)&B[(wc * 128 + ni * 16 + l15) * 32 + swq];
#pragma unroll
    for (int mi = 0; mi < 4; ++mi)
#pragma unroll
      for (int ni = 0; ni < 8; ++ni)
        acc[mi][ni] = __builtin_amdgcn_mfma_f32_16x16x32_bf16(
            af[mi], bfr[ni], acc[mi][ni], 0, 0, 0);
  };

#define WAIT6 asm volatile("s_waitcnt vmcnt(6)" ::: "memory")
#define WAIT0 asm volatile("s_waitcnt vmcnt(0)" ::: "memory")
#define BARR  __builtin_amdgcn_s_barrier()

  stage(0, A0, B0);
  stage(1, A1, B1);

  for (int g = 0; g < 47; ++g) {        // slots 0..140
    const int s = g * 3;
    WAIT6; BARR; stage(s + 2, A2, B2); compute(A0, B0);
    WAIT6; BARR; stage(s + 3, A0, B0); compute(A1, B1);
    WAIT6; BARR; stage(s + 4, A1, B1); compute(A2, B2);
  }
  WAIT6; BARR; stage(143, A2, B2); compute(A0, B0);     // slot 141
  WAIT6; BARR; compute(A1, B1);                         // slot 142
  WAIT0; BARR; compute(A2, B2);                         // slot 143

#undef WAIT6
#undef WAIT0
#undef BARR

  // epilogue: bias + relu, store bf16 NHWC mid[px][oc]
  const long px_base = (long)h0 * 128;    // 256 px contiguous
#pragma unroll
  for (int mi = 0; mi < 4; ++mi) {
    const int oc = oc_t * 128 + wr * 64 + mi * 16 + quad * 4;
    const float bv0 = b1[oc], bv1 = b1[oc + 1], bv2 = b1[oc + 2], bv3 = b1[oc + 3];
#pragma unroll
    for (int ni = 0; ni < 8; ++ni) {
      const int p = wc * 128 + ni * 16 + l15;
      f32x4 a = acc[mi][ni];
      float t0 = a[0] + bv0; t0 = t0 > 0.f ? t0 : 0.f;
      float t1 = a[1] + bv1; t1 = t1 > 0.f ? t1 : 0.f;
      float t2 = a[2] + bv2; t2 = t2 > 0.f ? t2 : 0.f;
      float t3 = a[3] + bv3; t3 = t3 > 0.f ? t3 : 0.f;
      bf16x4 v = {(bf16)t0, (bf16)t1, (bf16)t2, (bf16)t3};
      *(bf16x4*)(mid + (px_base + p) * 512 + oc) = v;
    }
  }
}

// ---------------- head: barrier-free K-split GEMM + anchor decode ----------
__global__ __launch_bounds__(256) void head_gemm(
    const bf16* __restrict__ w2p, const bf16* __restrict__ mid,
    const float* __restrict__ loc_b, const float* __restrict__ score_b,
    float* __restrict__ out) {
  __shared__ f32x4 red[3][64][5];
  const int tid  = threadIdx.x;
  const int wave = tid >> 6;
  const int lane = tid & 63;
  const int quad = lane >> 4;
  const int l15  = lane & 15;
  const int px0  = blockIdx.x * 16;
  const bf16* mB = mid + (long)px0 * 512;

  f32x4 acc[5];
#pragma unroll
  for (int i = 0; i < 5; ++i) acc[i] = (f32x4){0.f, 0.f, 0.f, 0.f};

#pragma unroll
  for (int st = 0; st < 4; ++st) {
    const int k0 = wave * 128 + st * 32;
    bf16x8 bfr = *(const bf16x8*)(mB + (long)l15 * 512 + k0 + quad * 8);
#pragma unroll
    for (int mi = 0; mi < 5; ++mi) {
      bf16x8 af = *(const bf16x8*)(w2p + (long)(mi * 16 + l15) * 512 + k0 + quad * 8);
      acc[mi] = __builtin_amdgcn_mfma_f32_16x16x32_bf16(af, bfr, acc[mi], 0, 0, 0);
    }
  }

  if (wave > 0) {
#pragma unroll
    for (int mi = 0; mi < 5; ++mi) red[wave - 1][lane][mi] = acc[mi];
  }
  __syncthreads();
  if (wave != 0) return;
#pragma unroll
  for (int w = 0; w < 3; ++w)
#pragma unroll
    for (int mi = 0; mi < 5; ++mi) acc[mi] += red[w][lane][mi];

  const int p    = px0 + l15;
  const int hh   = p >> 7;
  const int wcol = p & 127;
  const float cx = 16.f * (float)hh;
  const float cy = 16.f * (float)wcol;
  const float s0 = quad == 0 ? 45.f : quad == 1 ? 91.f : quad == 2 ? 181.f : 362.f;
  const float s1 = quad == 0 ? 32.f : quad == 1 ? 64.f : quad == 2 ? 128.f : 256.f;
  const float s2 = quad == 0 ? 23.f : quad == 1 ? 45.f : quad == 2 ? 91.f : 181.f;
  const float aw[3] = {s0, s1, s2};
  const float ah[3] = {s2, s1, s0};
#pragma unroll
  for (int mi = 0; mi < 5; ++mi) {
#pragma unroll
    for (int r = 0; r < 4; ++r) {
      const int oc2 = mi * 16 + quad * 4 + r;
      float v = acc[mi][r];
      if (mi < 3) {
        v += loc_b[oc2];
        out[p * 48 + oc2] = v;
        float roi;
        if (r == 0)      roi = v * aw[mi] + cx;
        else if (r == 1) roi = v * ah[mi] + cy;
        else if (r == 2) roi = __expf(v) * aw[mi];
        else             roi = __expf(v) * ah[mi];
        out[OUT_ROI + p * 48 + oc2] = roi;
      } else {
        const int sc = oc2 - 48;
        if (sc < 24) {
          v += score_b[sc];
          out[OUT_CLS + p * 24 + sc] = v;
        }
      }
    }
  }
}

// ---------------------------------------------------------------------------
extern "C" void kernel_launch(void* const* d_in, const int* in_sizes, int n_in,
                              void* d_out, int out_size, void* d_ws, size_t ws_size,
                              hipStream_t stream) {
  (void)in_sizes; (void)n_in; (void)out_size; (void)ws_size;
  const float* x       = (const float*)d_in[0];
  const float* conv1_w = (const float*)d_in[1];
  const float* conv1_b = (const float*)d_in[2];
  const float* score_w = (const float*)d_in[3];
  const float* score_b = (const float*)d_in[4];
  const float* loc_w   = (const float*)d_in[5];
  const float* loc_b   = (const float*)d_in[6];
  char* ws = (char*)d_ws;
  bf16* xh  = (bf16*)(ws + WS_XH);
  bf16* w1t = (bf16*)(ws + WS_W1T);
  bf16* w2p = (bf16*)(ws + WS_W2P);
  bf16* mid = (bf16*)(ws + WS_MID);
  float* out = (float*)d_out;

  hipLaunchKernelGGL(prep_all,   dim3(3364), dim3(256), 0, stream,
                     (int4*)xh, conv1_w, w1t, loc_w, score_w, w2p, x, xh);
  hipLaunchKernelGGL(conv1_gemm, dim3(256),  dim3(256), 0, stream, w1t, xh, conv1_b, mid);
  hipLaunchKernelGGL(head_gemm,  dim3(1024), dim3(256), 0, stream, w2p, mid, loc_b, score_b, out);
}

// Round 9
// 192.344 us; speedup vs baseline: 1.1170x; 1.1170x over previous
//
#include <hip/hip_runtime.h>
#include <hip/hip_cooperative_groups.h>

namespace cg = cooperative_groups;

typedef __bf16 bf16;
typedef __attribute__((ext_vector_type(8))) __bf16 bf16x8;
typedef __attribute__((ext_vector_type(4))) __bf16 bf16x4;
typedef __attribute__((ext_vector_type(4))) float f32x4;

__device__ __forceinline__ void gload16(const void* g, void* l) {
  __builtin_amdgcn_global_load_lds(
      (__attribute__((address_space(1))) void*)(g),
      (__attribute__((address_space(3))) void*)(l), 16, 0, 0);
}

// ---------------------------------------------------------------------------
// Workspace layout (bytes):
//   xh  : NHWC padded input, bf16 [130][130][512]        = 17,305,600
//   w1t : conv1 weights,     bf16 [9][512 oc][512 c]     =  4,718,592
//   w2p : packed head wts,   bf16 [80 oc2][512 c]        =     81,920
//   mid : conv1 output NHWC, bf16 [16384 px][512 oc]     = 16,777,216
// ---------------------------------------------------------------------------
#define WS_XH   0
#define WS_W1T  17305600
#define WS_W2P  22024192
#define WS_MID  22106112

#define OUT_CLS 786432
#define OUT_ROI 1179648

// ===========================================================================
// Shared device helpers — used by BOTH the fused cooperative kernel and the
// standalone fallback kernels (so fallback is the proven round-6 trio).
// ===========================================================================

// ---- prep unit u in [0,3364): border | w1 repack | w2 pack | transpose ----
__device__ __forceinline__ void dev_prep_unit(
    int u, int tid, char* smem, int4* __restrict__ xh4,
    const float* __restrict__ w1, bf16* __restrict__ w1t,
    const float* __restrict__ loc_w, const float* __restrict__ score_w,
    bf16* __restrict__ w2p, const float* __restrict__ x,
    bf16* __restrict__ xh) {
  float (*lds)[65] = (float(*)[65])smem;   // 64x65 f32
  float* ldsf = (float*)smem;              // 2304 f32 overlay
  if (u < 132) {                           // ---- xh halo border zeroing
    const int4 z = make_int4(0, 0, 0, 0);
    if (u < 130) {
      if (tid < 64)       xh4[(u * 130 + 0) * 64 + tid] = z;
      else if (tid < 128) xh4[(u * 130 + 129) * 64 + (tid - 64)] = z;
    } else {
      const int r = (u == 130) ? 0 : 129;
      for (int i = tid; i < 8320; i += 256) xh4[r * 8320 + i] = z;
    }
  } else if (u < 1156) {                   // ---- w1 -> w1t[j][oc][c]
    const int bb = u - 132;
    const long base = (long)bb * 2304;
#pragma unroll
    for (int i = 0; i < 9; ++i) ldsf[i * 256 + tid] = w1[base + i * 256 + tid];
    __syncthreads();
    const int pair0 = bb * 256;            // pair = oc*512 + c
#pragma unroll
    for (int j = 0; j < 9; ++j)
      w1t[(long)j * 262144 + pair0 + tid] = (bf16)ldsf[tid * 9 + j];
  } else if (u < 1316) {                   // ---- pack -> w2p[80][512]
    const int idx = (u - 1156) * 256 + tid;
    const int c  = idx & 511;
    const int oc = idx >> 9;
    float v = 0.f;
    if (oc < 48)      v = loc_w[oc * 512 + c];
    else if (oc < 72) v = score_w[(oc - 48) * 512 + c];
    w2p[idx] = (bf16)v;
  } else {                                 // ---- NCHW f32 -> NHWC bf16
    const int bb   = u - 1316;
    const int ct   = bb & 7;
    const int colt = (bb >> 3) & 1;
    const int r    = 1 + (bb >> 4);
    const int c0   = ct * 64;
    const int col0 = 1 + colt * 64;
    const int lcol = tid & 63;
    const int coff = tid >> 6;
#pragma unroll
    for (int i = 0; i < 16; ++i) {
      const int cl = coff + i * 4;
      lds[cl][lcol] = x[(long)(c0 + cl) * 16384 + (r - 1) * 128 + (col0 - 1) + lcol];
    }
    __syncthreads();
#pragma unroll
    for (int i = 0; i < 2; ++i) {
      const int idx = i * 256 + tid;
      const int pxl = idx >> 3;
      const int oct = idx & 7;
      bf16x8 v;
#pragma unroll
      for (int e = 0; e < 8; ++e) v[e] = (bf16)lds[oct * 8 + e][pxl];
      *(bf16x8*)(xh + (long)(r * 130 + col0 + pxl) * 512 + c0 + oct * 8) = v;
    }
  }
}

// ---- conv1 block (round-5/6 champion: 128x128 tile, 3-deep pipeline) ------
__device__ __forceinline__ void dev_conv(
    int blk, int tid, char* smem, const bf16* __restrict__ w1t,
    const bf16* __restrict__ xh, const float* __restrict__ b1,
    bf16* __restrict__ mid) {
  bf16* A0 = (bf16*)(smem);
  bf16* B0 = (bf16*)(smem + 8192);
  bf16* A1 = (bf16*)(smem + 16384);
  bf16* B1 = (bf16*)(smem + 24576);
  bf16* A2 = (bf16*)(smem + 32768);
  bf16* B2 = (bf16*)(smem + 40960);
  const int wave = tid >> 6;
  const int lane = tid & 63;
  const int quad = lane >> 4;
  const int l15  = lane & 15;
  const int wr = wave >> 1, wc = wave & 1;
  const int oc_tile = blk >> 7;
  const int hraw    = blk & 127;
  const int h       = ((hraw & 7) << 4) + (hraw >> 3);   // XCD h-band swizzle
  const char* w1tB = (const char*)w1t + (long)oc_tile * 131072;
  const char* xhB  = (const char*)xh;
  const int srow = lane >> 2;                               // 16 rows/call
  const int ssw  = (((lane & 3) ^ ((lane >> 3) & 3)) << 4); // swizzled chunk
  const int swq  = (quad ^ ((l15 >> 1) & 3)) << 3;          // swizzled frag

  auto stage = [&](int s, bf16* At, bf16* Bt) {   // 4 gloads per wave
    const int j  = s >> 4, ck = s & 15;
    const int ky = j / 3, kx = j - ky * 3;
    const char* aB = w1tB + (long)j * 524288 + ck * 64;
    const char* bB = xhB + (long)((h + ky) * 130 + kx) * 1024 + ck * 64;
#pragma unroll
    for (int c = 0; c < 2; ++c) {
      const int r0 = wave * 32 + c * 16;
      gload16(aB + (long)(r0 + srow) * 1024 + ssw, (char*)At + r0 * 64);
      gload16(bB + (long)(r0 + srow) * 1024 + ssw, (char*)Bt + r0 * 64);
    }
  };

  f32x4 acc[4][4];
#pragma unroll
  for (int i = 0; i < 4; ++i)
#pragma unroll
    for (int k = 0; k < 4; ++k) acc[i][k] = (f32x4){0.f, 0.f, 0.f, 0.f};

  auto compute = [&](const bf16* A, const bf16* B) {
    bf16x8 af[4], bfr[4];
#pragma unroll
    for (int mi = 0; mi < 4; ++mi)
      af[mi] = *(const bf16x8*)&A[(wr * 64 + mi * 16 + l15) * 32 + swq];
#pragma unroll
    for (int ni = 0; ni < 4; ++ni)
      bfr[ni] = *(const bf16x8*)&B[(wc * 64 + ni * 16 + l15) * 32 + swq];
#pragma unroll
    for (int mi = 0; mi < 4; ++mi)
#pragma unroll
      for (int ni = 0; ni < 4; ++ni)
        acc[mi][ni] = __builtin_amdgcn_mfma_f32_16x16x32_bf16(
            af[mi], bfr[ni], acc[mi][ni], 0, 0, 0);
  };

#define WAIT4 asm volatile("s_waitcnt vmcnt(4)" ::: "memory")
#define WAIT0 asm volatile("s_waitcnt vmcnt(0)" ::: "memory")
#define BARR  __builtin_amdgcn_s_barrier()

  stage(0, A0, B0);
  stage(1, A1, B1);
  for (int g = 0; g < 47; ++g) {        // slots 0..140
    const int s = g * 3;
    WAIT4; BARR; stage(s + 2, A2, B2); compute(A0, B0);
    WAIT4; BARR; stage(s + 3, A0, B0); compute(A1, B1);
    WAIT4; BARR; stage(s + 4, A1, B1); compute(A2, B2);
  }
  WAIT4; BARR; stage(143, A2, B2); compute(A0, B0);     // slot 141
  WAIT4; BARR; compute(A1, B1);                         // slot 142
  WAIT0; BARR; compute(A2, B2);                         // slot 143

#undef WAIT4
#undef WAIT0
#undef BARR

  // epilogue: bias + relu, store bf16 NHWC mid[px][oc]
#pragma unroll
  for (int mi = 0; mi < 4; ++mi) {
    const int oc = oc_tile * 128 + wr * 64 + mi * 16 + quad * 4;
    const float bv0 = b1[oc], bv1 = b1[oc + 1], bv2 = b1[oc + 2], bv3 = b1[oc + 3];
#pragma unroll
    for (int ni = 0; ni < 4; ++ni) {
      const int px = wc * 64 + ni * 16 + l15;
      f32x4 a = acc[mi][ni];
      float t0 = a[0] + bv0; t0 = t0 > 0.f ? t0 : 0.f;
      float t1 = a[1] + bv1; t1 = t1 > 0.f ? t1 : 0.f;
      float t2 = a[2] + bv2; t2 = t2 > 0.f ? t2 : 0.f;
      float t3 = a[3] + bv3; t3 = t3 > 0.f ? t3 : 0.f;
      bf16x4 v = {(bf16)t0, (bf16)t1, (bf16)t2, (bf16)t3};
      *(bf16x4*)(mid + (long)(h * 128 + px) * 512 + oc) = v;
    }
  }
}

// ---- head unit: 16 px starting at px0 (K-split + anchor decode) -----------
__device__ __forceinline__ void dev_head(
    int px0, int tid, char* smem, const bf16* __restrict__ w2p,
    const bf16* __restrict__ mid, const float* __restrict__ loc_b,
    const float* __restrict__ score_b, float* __restrict__ out) {
  f32x4 (*red)[64][5] = (f32x4(*)[64][5])smem;   // 15360 B
  const int wave = tid >> 6;
  const int lane = tid & 63;
  const int quad = lane >> 4;
  const int l15  = lane & 15;
  const bf16* mB = mid + (long)px0 * 512;

  f32x4 acc[5];
#pragma unroll
  for (int i = 0; i < 5; ++i) acc[i] = (f32x4){0.f, 0.f, 0.f, 0.f};
#pragma unroll
  for (int st = 0; st < 4; ++st) {
    const int k0 = wave * 128 + st * 32;
    bf16x8 bfr = *(const bf16x8*)(mB + (long)l15 * 512 + k0 + quad * 8);
#pragma unroll
    for (int mi = 0; mi < 5; ++mi) {
      bf16x8 af = *(const bf16x8*)(w2p + (long)(mi * 16 + l15) * 512 + k0 + quad * 8);
      acc[mi] = __builtin_amdgcn_mfma_f32_16x16x32_bf16(af, bfr, acc[mi], 0, 0, 0);
    }
  }

  __syncthreads();                 // WAR vs any prior use of smem
  if (wave > 0) {
#pragma unroll
    for (int mi = 0; mi < 5; ++mi) red[wave - 1][lane][mi] = acc[mi];
  }
  __syncthreads();
  if (wave == 0) {
#pragma unroll
    for (int w = 0; w < 3; ++w)
#pragma unroll
      for (int mi = 0; mi < 5; ++mi) acc[mi] += red[w][lane][mi];

    const int p    = px0 + l15;
    const int hh   = p >> 7;
    const int wcol = p & 127;
    const float cx = 16.f * (float)hh;
    const float cy = 16.f * (float)wcol;
    const float s0 = quad == 0 ? 45.f : quad == 1 ? 91.f : quad == 2 ? 181.f : 362.f;
    const float s1 = quad == 0 ? 32.f : quad == 1 ? 64.f : quad == 2 ? 128.f : 256.f;
    const float s2 = quad == 0 ? 23.f : quad == 1 ? 45.f : quad == 2 ? 91.f : 181.f;
    const float aw[3] = {s0, s1, s2};
    const float ah[3] = {s2, s1, s0};
#pragma unroll
    for (int mi = 0; mi < 5; ++mi) {
#pragma unroll
      for (int r = 0; r < 4; ++r) {
        const int oc2 = mi * 16 + quad * 4 + r;
        float v = acc[mi][r];
        if (mi < 3) {
          v += loc_b[oc2];
          out[p * 48 + oc2] = v;
          float roi;
          if (r == 0)      roi = v * aw[mi] + cx;
          else if (r == 1) roi = v * ah[mi] + cy;
          else if (r == 2) roi = __expf(v) * aw[mi];
          else             roi = __expf(v) * ah[mi];
          out[OUT_ROI + p * 48 + oc2] = roi;
        } else {
          const int sc = oc2 - 48;
          if (sc < 24) {
            v += score_b[sc];
            out[OUT_CLS + p * 24 + sc] = v;
          }
        }
      }
    }
  }
}

// ===========================================================================
// Fused cooperative kernel (1 dispatch) — 512 blocks x 256 thr, 2/CU.
// ===========================================================================
__global__ __launch_bounds__(256, 2) void rpn_all(
    const float* __restrict__ x, const float* __restrict__ w1,
    const float* __restrict__ b1,
    const float* __restrict__ score_w, const float* __restrict__ score_b,
    const float* __restrict__ loc_w, const float* __restrict__ loc_b,
    bf16* __restrict__ xh, bf16* __restrict__ w1t, bf16* __restrict__ w2p,
    bf16* __restrict__ mid, float* __restrict__ out) {
  __shared__ __align__(16) char smem[49152];
  const int tid = threadIdx.x;

  for (int u = blockIdx.x; u < 3364; u += 512) {
    dev_prep_unit(u, tid, smem, (int4*)xh, w1, w1t, loc_w, score_w, w2p, x, xh);
    __syncthreads();                     // LDS WAR across units
  }
  __threadfence();
  cg::this_grid().sync();

  dev_conv(blockIdx.x, tid, smem, w1t, xh, b1, mid);

  __threadfence();
  cg::this_grid().sync();

#pragma unroll
  for (int u = 0; u < 2; ++u)
    dev_head((blockIdx.x * 2 + u) * 16, tid, smem, w2p, mid, loc_b, score_b, out);
}

// ===========================================================================
// Fallback standalone kernels (round-6 proven trio).
// ===========================================================================
__global__ __launch_bounds__(256) void prep_all(
    int4* __restrict__ xh4, const float* __restrict__ w1,
    bf16* __restrict__ w1t, const float* __restrict__ loc_w,
    const float* __restrict__ score_w, bf16* __restrict__ w2p,
    const float* __restrict__ x, bf16* __restrict__ xh) {
  __shared__ __align__(16) char smem[16640];
  dev_prep_unit(blockIdx.x, threadIdx.x, smem, xh4, w1, w1t, loc_w, score_w,
                w2p, x, xh);
}

__global__ __launch_bounds__(256, 2) void conv1_gemm(
    const bf16* __restrict__ w1t, const bf16* __restrict__ xh,
    const float* __restrict__ b1, bf16* __restrict__ mid) {
  __shared__ __align__(16) char smem[49152];
  dev_conv(blockIdx.x, threadIdx.x, smem, w1t, xh, b1, mid);
}

__global__ __launch_bounds__(256) void head_gemm(
    const bf16* __restrict__ w2p, const bf16* __restrict__ mid,
    const float* __restrict__ loc_b, const float* __restrict__ score_b,
    float* __restrict__ out) {
  __shared__ __align__(16) char smem[15360];
  dev_head(blockIdx.x * 16, threadIdx.x, smem, w2p, mid, loc_b, score_b, out);
}

// ---------------------------------------------------------------------------
extern "C" void kernel_launch(void* const* d_in, const int* in_sizes, int n_in,
                              void* d_out, int out_size, void* d_ws, size_t ws_size,
                              hipStream_t stream) {
  (void)in_sizes; (void)n_in; (void)out_size; (void)ws_size;
  const float* x       = (const float*)d_in[0];
  const float* conv1_w = (const float*)d_in[1];
  const float* conv1_b = (const float*)d_in[2];
  const float* score_w = (const float*)d_in[3];
  const float* score_b = (const float*)d_in[4];
  const float* loc_w   = (const float*)d_in[5];
  const float* loc_b   = (const float*)d_in[6];
  char* ws = (char*)d_ws;
  bf16* xh  = (bf16*)(ws + WS_XH);
  bf16* w1t = (bf16*)(ws + WS_W1T);
  bf16* w2p = (bf16*)(ws + WS_W2P);
  bf16* mid = (bf16*)(ws + WS_MID);
  float* out = (float*)d_out;

  // ---- stateless gating: cooperative-launch viability (host queries only) --
  int dev = 0;
  (void)hipGetDevice(&dev);
  int coopAttr = 0;
  (void)hipDeviceGetAttribute(&coopAttr, hipDeviceAttributeCooperativeLaunch, dev);
  bool coop = (coopAttr != 0);
  if (coop) {
    int maxBlk = 0;
    hipError_t oe = hipOccupancyMaxActiveBlocksPerMultiprocessor(
        &maxBlk, rpn_all, 256, 0);
    if (oe != hipSuccess || maxBlk < 2) coop = false;
  }
  if (coop) {
    void* args[] = {&x, &conv1_w, &conv1_b, &score_w, &score_b, &loc_w, &loc_b,
                    &xh, &w1t, &w2p, &mid, &out};
    hipError_t le = hipLaunchCooperativeKernel((void*)rpn_all, dim3(512),
                                               dim3(256), args, 0, stream);
    if (le == hipSuccess) return;
  }

  // ---- fallback: proven 3-dispatch path (round-6 champion) ----------------
  hipLaunchKernelGGL(prep_all,   dim3(3364), dim3(256), 0, stream,
                     (int4*)xh, conv1_w, w1t, loc_w, score_w, w2p, x, xh);
  hipLaunchKernelGGL(conv1_gemm, dim3(512),  dim3(256), 0, stream,
                     w1t, xh, conv1_b, mid);
  hipLaunchKernelGGL(head_gemm,  dim3(1024), dim3(256), 0, stream,
                     w2p, mid, loc_b, score_b, out);
}